// Round 3
// baseline (205.004 us; speedup 1.0000x reference)
//
#include <hip/hip_runtime.h>
#include <hip/hip_bf16.h>
#include <math.h>

#define B_   4
#define T_   4096
#define DIN_ 1024
#define H_   16
#define D_   64
#define M_   (B_*T_)      // 16384
#define N_   (H_*D_*2)    // 2048
#define K_   DIN_         // 1024
#define C_   64           // scan chunks per (b,h) chain
#define CL_  (T_/C_)      // 64 steps per chunk

typedef unsigned short u16;
typedef __attribute__((ext_vector_type(8))) short short8_t;
typedef __attribute__((ext_vector_type(4))) float float4_t;

__device__ __forceinline__ u16 f2bf(float f) {
  unsigned int x = __float_as_uint(f);
  x += 0x7fffu + ((x >> 16) & 1u);   // round-to-nearest-even (finite inputs)
  return (u16)(x >> 16);
}
__device__ __forceinline__ float bf2f(unsigned int u) {
  return __uint_as_float((u & 0xffffu) << 16);
}
__device__ __forceinline__ unsigned pk_bf16(float x, float y) {
  float2 f; f.x = x; f.y = y;
  union { __hip_bfloat162 h2; unsigned u; } c;
  c.h2 = __float22bfloat162_rn(f);
  return c.u;
}

// async global->LDS, 16 B per lane. LDS dest = wave-uniform base + lane*16.
__device__ __forceinline__ void g2l16(const u16* g, u16* l) {
  __builtin_amdgcn_global_load_lds(
      (const __attribute__((address_space(1))) void*)g,
      (__attribute__((address_space(3))) void*)l, 16, 0, 0);
}

// ---------------- prep: cast inputs + cast-transpose weights (unchanged) ----------------
__global__ __launch_bounds__(256)
void prep(const float* __restrict__ inputs, const float* __restrict__ kvk,
          u16* __restrict__ aB, u16* __restrict__ wBt) {
  __shared__ float tile[32][33];
  int bid = blockIdx.x;
  int tid = threadIdx.x;
  if (bid < 8192) {
    int i = bid * 256 + tid;          // over M*K/8
    const float4* src = (const float4*)inputs;
    float4 a = src[2*i], b = src[2*i+1];
    uint4 o;
    o.x = pk_bf16(a.x, a.y);
    o.y = pk_bf16(a.z, a.w);
    o.z = pk_bf16(b.x, b.y);
    o.w = pk_bf16(b.z, b.w);
    ((uint4*)aB)[i] = o;
  } else {
    int b2 = bid - 8192;              // 2048 blocks
    int kb = (b2 & 31) * 32;          // K/32 = 32
    int nb = (b2 >> 5) * 32;          // N/32 = 64
    int r  = tid >> 3;                // 0..31
    int c4 = (tid & 7) * 4;           // 0..28
    float4 v = *(const float4*)&kvk[(size_t)(kb + r) * N_ + nb + c4];
    tile[r][c4+0] = v.x; tile[r][c4+1] = v.y; tile[r][c4+2] = v.z; tile[r][c4+3] = v.w;
    __syncthreads();
    uint2 o;
    o.x = pk_bf16(tile[c4+0][r], tile[c4+1][r]);
    o.y = pk_bf16(tile[c4+2][r], tile[c4+3][r]);
    *(uint2*)&wBt[(size_t)(nb + r) * K_ + kb + c4] = o;
  }
}

// ---------------- gemm_kv: 256x256 tile, 8-phase counted-vmcnt K-loop (UNCHANGED) -------
// + R3 epilogue: vtile [hh][d][t] (stride 264, t-XOR swizzle), t-pair-packed b32
// transpose writes, shuffle-reduced U, chunked vbuf layout [bh][t/8][d][8].

#define FENCE asm volatile("" ::: "memory")
#define KBAR do { FENCE; __builtin_amdgcn_s_barrier(); FENCE; } while (0)

#define STAGE_A(P, KT, CC) do { \
  g2l16(gA + ((size_t)((CC)*64      ) * K_ + (KT)*64), lds + (P)*16384 +        (CC)*4096 + wv*512); \
  g2l16(gA + ((size_t)((CC)*64 + 128) * K_ + (KT)*64), lds + (P)*16384 + 8192 + (CC)*4096 + wv*512); \
} while (0)

#define STAGE_B(P, KT, HH) do { \
  g2l16(gB + ((size_t)((HH)*128     ) * K_ + (KT)*64), lds + 32768 + (P)*16384 + (HH)*8192 +        wv*512); \
  g2l16(gB + ((size_t)((HH)*128 + 64) * K_ + (KT)*64), lds + 32768 + (P)*16384 + (HH)*8192 + 4096 + wv*512); \
} while (0)

#define READ_A(P, MH) do { _Pragma("unroll") \
  for (int il_ = 0; il_ < 4; ++il_) { \
    const int o_ = (P)*16384 + aBase + (MH)*4096 + il_*1024; \
    af[il_][0] = *(const short8_t*)&lds[o_ + s0]; \
    af[il_][1] = *(const short8_t*)&lds[o_ + s1]; \
  } } while (0)

#define READ_B(P, NH) do { _Pragma("unroll") \
  for (int jl_ = 0; jl_ < 2; ++jl_) { \
    const int o_ = (P)*16384 + (NH)*8192 + bBase + jl_*1024; \
    bfr[NH][jl_][0] = *(const short8_t*)&lds[o_ + s0]; \
    bfr[NH][jl_][1] = *(const short8_t*)&lds[o_ + s1]; \
  } } while (0)

#define MFMA_Q(MH, NH) do { \
  __builtin_amdgcn_s_setprio(1); \
  _Pragma("unroll") for (int kk_ = 0; kk_ < 2; ++kk_) \
  _Pragma("unroll") for (int il_ = 0; il_ < 4; ++il_) \
  _Pragma("unroll") for (int jl_ = 0; jl_ < 2; ++jl_) \
    acc[(MH)*4+il_][(NH)*2+jl_] = __builtin_amdgcn_mfma_f32_16x16x32_bf16( \
        af[il_][kk_], bfr[NH][jl_][kk_], acc[(MH)*4+il_][(NH)*2+jl_], 0, 0, 0); \
  __builtin_amdgcn_s_setprio(0); \
} while (0)

#define VST_ 264   // vtile row stride in u16 (264*2=528 B, 16B-aligned rows)

__global__ __launch_bounds__(512, 2)
void gemm_kv(const u16* __restrict__ A, const u16* __restrict__ Bt,
             const float* __restrict__ q,
             float* __restrict__ pbuf, u16* __restrict__ vbuf,
             float* __restrict__ aggU, float* __restrict__ aggW) {
  extern __shared__ __align__(16) char smem[];
  u16* lds = (u16*)smem;

  const int tid  = threadIdx.x;
  const int wv   = tid >> 6;
  const int lane = tid & 63;
  const int quad = lane >> 4;
  const int l16  = lane & 15;
  const int wr   = wv >> 2;           // 0..1  (m: 128-row half)
  const int wc   = wv & 3;            // 0..3  (n: 32 cols of each head)

  // XCD-aware bijective swizzle (512 % 8 == 0); same-XCD blocks share mt range.
  const int g  = blockIdx.x;
  const int wg = (g & 7) * 64 + (g >> 3);
  const int nt = wg & 7;              // 0..7  -> heads {2nt, 2nt+1}
  const int mt = wg >> 3;             // 0..63 -> rows [mt*256, +256)
  const int bm = mt * 256;
  const int bn = nt * 256;

  // staging decomposition: thread -> (row-in-call, 16B granule), src pre-XOR'd
  const int tr   = tid >> 3;          // 0..63
  const int gran = tid & 7;
  const u16* gA = A  + (size_t)(bm + tr) * K_ + ((gran ^ (tr & 7)) * 8);
  const u16* gB = Bt + (size_t)(bn + tr) * K_ + ((gran ^ (tr & 7)) * 8);

  // fragment ds_read bases (u16 units); XOR matches staged layout
  const int s0 = ((quad    ) ^ (l16 & 7)) * 8;
  const int s1 = ((quad + 4) ^ (l16 & 7)) * 8;
  const int aBase = wr * 8192 + l16 * 64;           // + P*16384 + MH*4096 + il*1024
  const int bBase = 32768 + wc * 2048 + l16 * 64;   // + P*16384 + NH*8192 + jl*1024

  float4_t acc[8][4] = {};
  short8_t af[4][2];
  short8_t bfr[2][2][2];

  // prologue: kt0 full (8 loads) + kt1 A.c0/B.h0 (4 loads); keep kt1's 4 in flight
  STAGE_A(0, 0, 0); STAGE_A(0, 0, 1);
  STAGE_B(0, 0, 0); STAGE_B(0, 0, 1);
  STAGE_A(1, 1, 0); STAGE_B(1, 1, 0);
  asm volatile("s_waitcnt vmcnt(4)" ::: "memory");
  KBAR;

#pragma unroll 1
  for (int it = 0; it < 8; ++it) {
    const int kt1 = 2*it + 1, kt2 = 2*it + 2, kt3 = 2*it + 3;
    const bool more = (it < 7);
    // ph0
    READ_A(0, 0); READ_B(0, 0);
    STAGE_A(1, kt1, 1);
    KBAR;
    MFMA_Q(0, 0);
    KBAR;
    // ph1
    READ_B(0, 1);
    STAGE_B(1, kt1, 1);
    KBAR;
    MFMA_Q(0, 1);
    KBAR;
    // ph2
    READ_A(0, 1);
    if (more) STAGE_A(0, kt2, 0);
    KBAR;
    MFMA_Q(1, 0);
    KBAR;
    // ph3 (+ parity checkpoint)
    if (more) STAGE_B(0, kt2, 0);
    KBAR;
    MFMA_Q(1, 1);
    if (more) asm volatile("s_waitcnt vmcnt(4)" ::: "memory");
    else      asm volatile("s_waitcnt vmcnt(0)" ::: "memory");
    KBAR;
    // ph4
    READ_A(1, 0); READ_B(1, 0);
    if (more) STAGE_A(0, kt2, 1);
    KBAR;
    MFMA_Q(0, 0);
    KBAR;
    // ph5
    READ_B(1, 1);
    if (more) STAGE_B(0, kt2, 1);
    KBAR;
    MFMA_Q(0, 1);
    KBAR;
    // ph6
    READ_A(1, 1);
    if (more) STAGE_A(1, kt3, 0);
    KBAR;
    MFMA_Q(1, 0);
    KBAR;
    // ph7 (+ parity checkpoint)
    if (more) STAGE_B(1, kt3, 0);
    KBAR;
    MFMA_Q(1, 1);
    if (more) asm volatile("s_waitcnt vmcnt(4)" ::: "memory");
    KBAR;
  }

  // ---------------- fused epilogue (R3) ----------------
  // C/D frag layout: col(n) = l16, row(m) = quad*4 + reg.
  // t = wr*128 + i*16 + quad*4 + r;  head = nh;  n' = wc*32 + jl*16 + l16.
  // odd n' (odd l16) -> v column d = wc*16 + jl*8 + (l16>>1); even -> k column.
  // vtile: [2 hh][64 d][264 t-pad] u16, t XOR-swizzled by ((d>>3)&3)<<3.
  u16*   vtile = (u16*)smem;                   // 2*64*264*2 = 67584 B
  float* sred  = (float*)(smem + 67584);       // [2][256][17] f32 = 34816 B
  float* pS    = (float*)(smem + 102400);      // [2][256]     f32 =  2048 B (ends 104448)

  float qv[2][2];
#pragma unroll
  for (int nh = 0; nh < 2; ++nh)
#pragma unroll
    for (int jl = 0; jl < 2; ++jl)
      qv[nh][jl] = q[nt*128 + nh*64 + wc*16 + jl*8 + (l16 >> 1)];

#pragma unroll
  for (int nh = 0; nh < 2; ++nh) {
#pragma unroll
    for (int i = 0; i < 8; ++i) {
      float x0[4], x1[4];
#pragma unroll
      for (int r = 0; r < 4; ++r) {
        x0[r] = fmaxf(acc[i][nh*2+0][r], 0.f);
        x1[r] = fmaxf(acc[i][nh*2+1][r], 0.f);
      }
      const int tb = wr*128 + i*16 + quad*4;
      if (l16 & 1) {
        // v columns: pack along t (r, r+1 adjacent in [d][t] layout)
        const int d0 = wc*16 + (l16 >> 1);     // jl=0 column
        const int sA = ((d0 >> 3) & 3) << 3;
        const int sB = (((d0+8) >> 3) & 3) << 3;
#pragma unroll
        for (int rp = 0; rp < 4; rp += 2) {
          const int t = tb + rp;               // even
          *(unsigned*)&vtile[(nh*64 + d0    )*VST_ + (t ^ sA)] = pk_bf16(x0[rp], x0[rp+1]);
          *(unsigned*)&vtile[(nh*64 + d0 + 8)*VST_ + (t ^ sB)] = pk_bf16(x1[rp], x1[rp+1]);
        }
      } else {
        // k columns: q-dot partials -> sred
#pragma unroll
        for (int r = 0; r < 4; ++r) {
          const int t = tb + r;
          float ps = qv[nh][0]*x0[r] + qv[nh][1]*x1[r];
          ps += __shfl_xor(ps, 2);
          if ((l16 & 3) == 0)
            sred[(nh*256 + t)*17 + wc*4 + (l16 >> 2)] = ps;
        }
      }
    }
  }
  __syncthreads();

  const int b  = mt >> 4;             // 16 m-tiles per batch
  const int t0 = (mt & 15) * 256;
  {
    // p-phase: s reduction -> p = exp(clamp(s)); wave = one (hh, chunk) -> U shfl-reduce
    const int hh = tid >> 8;          // head-local 0/1
    const int t  = tid & 255;
    float s = 0.f;
#pragma unroll
    for (int k = 0; k < 16; ++k) s += sred[(hh*256 + t)*17 + k];
    float p = __expf(fminf(fmaxf(s, -60.f), 60.f));
    pS[hh*256 + t] = p;
    pbuf[(size_t)(b*H_ + nt*2 + hh) * T_ + t0 + t] = p;
    float u = p;
#pragma unroll
    for (int off = 32; off; off >>= 1) u += __shfl_down(u, off);
    if (lane == 0) {
      const int ch = (tid >> 6) & 3;  // chunk within this head's 256 t
      aggU[(b*H_ + nt*2 + hh)*C_ + (mt & 15)*4 + ch] = u;
    }
  }
  __syncthreads();

  {
    // pass1 W: wave = (hh, chunk); lane = d
    const int hh = wv >> 2;           // 0/1
    const int ch = wv & 3;            // chunk 0..3 (64 t each)
    const int d  = lane;
    const int sK = ((d >> 3) & 3) << 3;
    float W = 0.f;
#pragma unroll 8
    for (int i2 = 0; i2 < CL_; ++i2) {
      const int t = ch*CL_ + i2;
      float p = pS[hh*256 + t];
      float v = bf2f(vtile[(hh*64 + d)*VST_ + (t ^ sK)]);
      W += p * v;
    }
    const int blk = (b*H_ + nt*2 + hh)*C_ + (mt & 15)*4 + ch;
    aggW[(size_t)blk * D_ + d] = W;
  }
  {
    // v store: chunked layout vbuf[bh][tc=t/8][d][8] u16; 1KB per wave-instr
    const int d  = tid & 63;
    const int kk = tid >> 6;          // 0..7
    const int sK = ((d >> 3) & 3) << 3;
    const int tc0 = (mt & 15) * 32;   // global 8-t chunk base
#pragma unroll
    for (int hh = 0; hh < 2; ++hh) {
#pragma unroll
      for (int j = 0; j < 4; ++j) {
        const int k  = kk + 8*j;      // local chunk 0..31
        const int gI = (k*8) ^ sK;    // swizzled vtile t-group base
        uint4 val = *(const uint4*)&vtile[(hh*64 + d)*VST_ + gI];
        const size_t bh = (size_t)(b*H_ + nt*2 + hh);
        *(uint4*)&vbuf[((bh*512 + tc0 + k)*64 + d)*8] = val;
      }
    }
  }
}

// ---------------- pass 3: additive prefix + seeded scan + h-reduction ----------------
// R3: v reads are 8 upfront dwordx4 chunk loads per (h,d) chain (vbuf chunked layout).
__global__ __launch_bounds__(1024)
void scan_pass3(const u16* __restrict__ vbuf, const float* __restrict__ pbuf,
                const float* __restrict__ aggU, const float* __restrict__ aggW,
                float* __restrict__ out) {
  __shared__ float pS[H_][CL_];         // 4 KB
  __shared__ float wbuf[H_][8][D_ + 1]; // 33.3 KB
  int bc = blockIdx.x;
  int b  = bc >> 6;
  int c  = bc & (C_ - 1);
  int tid  = threadIdx.x;
  int h    = tid >> 6;
  int lane = tid & 63;
  int bh   = b * H_ + h;
  int t0   = c * CL_;

  pS[h][lane] = pbuf[(size_t)bh * T_ + t0 + lane];

  // all 8 v-chunks upfront: independent dwordx4, coalesced across lanes (d)
  uint4 vq[8];
  {
    const uint4* vb4 = (const uint4*)vbuf + ((size_t)bh*512 + (t0 >> 3))*64 + lane;
#pragma unroll
    for (int gq = 0; gq < 8; ++gq) vq[gq] = vb4[(size_t)gq * 64];
  }

  // additive exclusive prefix over chunks [0,c): independent loads, pipelines freely
  float U = 0.f, W = 0.f;
  for (int j = 0; j < c; ++j) {
    int idx = bh * C_ + j;
    U += aggU[idx];
    W += aggW[(size_t)idx * D_ + lane];
  }
  __syncthreads();

  for (int gg = 0; gg < 8; ++gg) {
    unsigned wa[4] = { vq[gg].x, vq[gg].y, vq[gg].z, vq[gg].w };
#pragma unroll
    for (int ii = 0; ii < 8; ++ii) {
      float p = pS[h][gg*8 + ii];
      unsigned word = wa[ii >> 1];
      float v = bf2f((ii & 1) ? (word >> 16) : word);
      U += p;
      W += p * v;
      wbuf[h][ii][lane] = __fdividef(W, U);
    }
    __syncthreads();
    if (tid < 512) {
      int ii = tid >> 6, dd = tid & 63;
      float acc = 0.f;
#pragma unroll
      for (int hh = 0; hh < H_; ++hh) acc += wbuf[hh][ii][dd];
      out[((size_t)b * T_ + t0 + gg*8 + ii) * D_ + dd] = acc;
    }
    __syncthreads();
  }
}

extern "C" void kernel_launch(void* const* d_in, const int* in_sizes, int n_in,
                              void* d_out, int out_size, void* d_ws, size_t ws_size,
                              hipStream_t stream) {
  const float* inputs = (const float*)d_in[0];   // (B,T,DIN)
  const float* kvk    = (const float*)d_in[1];   // (DIN,H,D,2)
  const float* qk     = (const float*)d_in[2];   // (H,D)
  float* out = (float*)d_out;
  char* ws = (char*)d_ws;

  u16*   aB   = (u16*)ws;                       // 33,554,432 B  inputs bf16 [M][K]
  u16*   wBt  = (u16*)(ws + 33554432);          //  4,194,304 B  weights bf16 [N][K]
  u16*   vb   = (u16*)(ws + 37748736);          // 33,554,432 B  v bf16 [bh][t/8][d][8]
  float* pb   = (float*)(ws + 71303168);        //  1,048,576 B  p=exp(s) [b,h,t]
  float* aggU = (float*)(ws + 72351744);        //     16,384 B
  float* aggW = (float*)(ws + 72368128);        //  1,048,576 B  (ends ~73.4 MB)

  prep<<<10240, 256, 0, stream>>>(inputs, kvk, aB, wBt);
  gemm_kv<<<512, 512, 131072, stream>>>(aB, wBt, qk, pb, vb, aggU, aggW);
  scan_pass3<<<B_*C_, 1024, 0, stream>>>(vb, pb, aggU, aggW, out);
}